// Round 10
// baseline (289.192 us; speedup 1.0000x reference)
//
#include <hip/hip_runtime.h>

typedef __bf16 bf16;
typedef __bf16 bf16x8 __attribute__((ext_vector_type(8)));
typedef __bf16 bf16x4 __attribute__((ext_vector_type(4)));
typedef float floatx4 __attribute__((ext_vector_type(4)));
typedef int   intx4  __attribute__((ext_vector_type(4)));
typedef int   intx2  __attribute__((ext_vector_type(2)));

#define MFMA16(a,b,c) __builtin_amdgcn_mfma_f32_16x16x32_bf16((a),(b),(c),0,0,0)

constexpr int Bc  = 4;
constexpr int Sc  = 2048;
constexpr int Hc  = 1024;
constexpr int NHc = 16;
constexpr int HDc = 64;
constexpr int Mc  = Bc * Sc;       // 8192 rows
constexpr int KIT = Hc / 32;       // 32 k-iterations
constexpr float L2E = 1.44269504088896f;

union U64  { bf16x4 h; intx2 i; };

// async global->LDS, 16B per lane (dest must be wave-uniform base + lane*16)
__device__ __forceinline__ void ld16(const bf16* g, bf16* l) {
    __builtin_amdgcn_global_load_lds(
        (const __attribute__((address_space(1))) void*)g,
        (__attribute__((address_space(3))) void*)l, 16, 0, 0);
}

// ---------------------------------------------------------------------------
// Inline per-block dtype detect: 256 threads read the first 256 ushorts of x
// (512B, L2-broadcast), treat each as truncated fp32, wave-parallel max.
// ---------------------------------------------------------------------------
__device__ __forceinline__ int detect_flag_block(const void* x, float* wmx)
{
    const unsigned short* xs = (const unsigned short*)x;
    const int tt = threadIdx.x;            // 256 threads, one value each
    unsigned int bits = ((unsigned int)xs[tt]) << 16;
    float v = __uint_as_float(bits);
    float a = isfinite(v) ? fabsf(v) : 1e30f;
#pragma unroll
    for (int off = 1; off < 64; off <<= 1)
        a = fmaxf(a, __shfl_xor(a, off, 64));
    if ((tt & 63) == 0) wmx[tt >> 6] = a;
    __syncthreads();
    const float m = fmaxf(fmaxf(wmx[0], wmx[1]), fmaxf(wmx[2], wmx[3]));
    __syncthreads();                       // wmx reusable after this
    return (m > 1e6f) ? 1 : 0;
}

// ---------------------------------------------------------------------------
// One merged conversion kernel: x (1048576 g8) | 4 weights (524288 g8) |
// mask+6 vectors (1792 g8)
// ---------------------------------------------------------------------------
__global__ __launch_bounds__(256)
void conv_all_k(const void* __restrict__ x,
                const void* __restrict__ Wq, const void* __restrict__ Wk,
                const void* __restrict__ Wv, const void* __restrict__ Wo,
                const void* __restrict__ mask,
                const void* __restrict__ bq, const void* __restrict__ bk,
                const void* __restrict__ bv, const void* __restrict__ bo,
                const void* __restrict__ lnw, const void* __restrict__ lnb,
                bf16* __restrict__ xb, bf16* __restrict__ wdst,
                float* maskf, float* bqf, float* bkf, float* bvf,
                float* bof, float* lnwf, float* lnbf)
{
    __shared__ float wmx[4];
    const int fl = detect_flag_block(x, wmx);

    const int g = blockIdx.x * 256 + threadIdx.x;
    if (g < 1048576) {
        if (fl) {
            const float* s = (const float*)x + (size_t)g * 8;
            union { intx4 v; bf16 e[8]; } o;
#pragma unroll
            for (int j = 0; j < 8; ++j) o.e[j] = (bf16)s[j];
            *(intx4*)(xb + (size_t)g * 8) = o.v;
        } else {
            *(intx4*)(xb + (size_t)g * 8) = *((const intx4*)x + g);
        }
    } else if (g < 1048576 + 524288) {
        const int gw = g - 1048576;
        const int wsel = gw >> 17, go = gw & 131071;
        const void* s = (wsel == 0) ? Wq : (wsel == 1) ? Wk : (wsel == 2) ? Wv : Wo;
        if (fl) {
            const float* sp = (const float*)s + (size_t)go * 8;
            union { intx4 v; bf16 e[8]; } o;
#pragma unroll
            for (int j = 0; j < 8; ++j) o.e[j] = (bf16)sp[j];
            *(intx4*)(wdst + (size_t)gw * 8) = o.v;
        } else {
            *(intx4*)(wdst + (size_t)gw * 8) = *((const intx4*)s + go);
        }
    } else {
        const int gs = g - 1048576 - 524288;
        if (gs >= 1792) return;
        const void* src; float* dst; int off; float scl = 1.0f;
        if (gs < 1024) { src = mask; dst = maskf; off = gs * 8; scl = L2E; }
        else {
            const int a = (gs - 1024) >> 7;
            off = ((gs - 1024) & 127) * 8;
            switch (a) {
                case 0: src = bq;  dst = bqf;  break;
                case 1: src = bk;  dst = bkf;  break;
                case 2: src = bv;  dst = bvf;  break;
                case 3: src = bo;  dst = bof;  break;
                case 4: src = lnw; dst = lnwf; break;
                default: src = lnb; dst = lnbf; break;
            }
        }
        if (fl) {
            const float* s = (const float*)src + off;
#pragma unroll
            for (int j = 0; j < 8; ++j) dst[off + j] = s[j] * scl;
        } else {
            union { intx4 v; bf16 e[8]; } u;
            u.v = *(const intx4*)((const bf16*)src + off);
#pragma unroll
            for (int j = 0; j < 8; ++j) dst[off + j] = (float)u.e[j] * scl;
        }
    }
}

// ---------------------------------------------------------------------------
// GEMM core: 128(M) x 256(N) tile over K=1024, A/W row-major, 512 threads
// (8 waves = 2M x 4N, per-wave 64x64 output -- same per-wave register and
// instruction mix as the proven 128^2/4-wave shape, but 25% less staging
// traffic per output elem and half the blocks). 2-phase pipelined dbuf,
// stage(kb+1) BEFORE ds_read+MFMA of kb, ONE barrier per K-step.
// As: 2 x 4096 elems (A tile 128x32); Bs: 2 x 8192 elems (B tile 256x32).
// SWAP=0: acc[i][j] = C[xrow-block i][feat-block j]
// SWAP=1: acc[i][j] = C[feat-block j][xrow-block i] (lane cols = xrow)
// ---------------------------------------------------------------------------
template<int SWAP>
__device__ __forceinline__
void gemm_core(const bf16* __restrict__ A, const bf16* __restrict__ W,
               int m0, int n0, int t, bf16* As, bf16* Bs, floatx4 (&acc)[4][4])
{
    const int l  = t & 63, w = t >> 6;  // w 0..7
    const int wr = w >> 2, wc = w & 3;  // 2M x 4N
    const int lq = l >> 4, ln = l & 15;
    const int sr = t >> 2;              // 0..127
    const int sc = (t & 3) * 8;         // 0,8,16,24

    const bf16* a0 = A + (size_t)(m0 + sr) * Hc + sc;         // A rows 0..127
    const bf16* b0 = W + (size_t)(n0 + sr) * Hc + sc;         // B rows 0..127
    const bf16* b1 = W + (size_t)(n0 + 128 + sr) * Hc + sc;   // B rows 128..255
    const int dst = sr * 32 + sc;       // lane-linear within a tile

    auto stage = [&](int buf, int kb) {
        const int off = kb * 32;
        ld16(a0 + off, As + buf * 4096 + dst);
        ld16(b0 + off, Bs + buf * 8192 + dst);
        ld16(b1 + off, Bs + buf * 8192 + 4096 + dst);
    };

    stage(0, 0);
    int cur = 0;
    for (int kb = 0; kb < KIT; ++kb) {
        __syncthreads();                 // buf[cur] ready; buf[cur^1] readers done
        if (kb + 1 < KIT) stage(cur ^ 1, kb + 1);

        const bf16* Ab = As + cur * 4096;
        const bf16* Bb = Bs + cur * 8192;
        bf16x8 af[4], bw[4];
#pragma unroll
        for (int i = 0; i < 4; ++i)
            af[i] = *(const bf16x8*)&Ab[(wr * 64 + i * 16 + ln) * 32 + lq * 8];
#pragma unroll
        for (int j = 0; j < 4; ++j)
            bw[j] = *(const bf16x8*)&Bb[(wc * 64 + j * 16 + ln) * 32 + lq * 8];

        __builtin_amdgcn_s_setprio(1);
#pragma unroll
        for (int i = 0; i < 4; ++i)
#pragma unroll
            for (int j = 0; j < 4; ++j)
                acc[i][j] = SWAP ? MFMA16(bw[j], af[i], acc[i][j])
                                 : MFMA16(af[i], bw[j], acc[i][j]);
        __builtin_amdgcn_s_setprio(0);
        cur ^= 1;
    }
}

// chunked XCD remap for the (4 x 64) = 256-tile grid: each XCD owns 32
// consecutive tiles = a 1024-row A-panel (2 MB) + full W (2 MB) -> 4 MB L2.
// Bijective (256 % 8 == 0).
__device__ __forceinline__ void xcd_remap(int bx, int by, int& m0, int& n0)
{
    const int f  = by * 4 + bx;              // dispatch-linear id, 0..255
    const int rm = (f & 7) * 32 + (f >> 3);  // XCD-chunked
    m0 = (rm >> 2) * 128;
    n0 = (rm & 3) * 256;
}

// ---------------------------------------------------------------------------
// Fused QKV: z=0 -> q (scaled by 0.125*log2e) [B,NH,S,HD]; z=1 -> k;
// z=2 -> V^T [B,NH,HD,S] via LDS transpose (4 head-chunks of 64 cols)
// 512 threads, launch_bounds(512,4): VGPR cap 128 -> 2 blocks/CU.
// ---------------------------------------------------------------------------
__global__ __launch_bounds__(512, 4)
void qkv_gemm(const bf16* __restrict__ x,
              const bf16* __restrict__ Wq, const float* __restrict__ bq,
              const bf16* __restrict__ Wk, const float* __restrict__ bk,
              const bf16* __restrict__ Wv, const float* __restrict__ bv,
              bf16* __restrict__ qo, bf16* __restrict__ ko, bf16* __restrict__ vto)
{
    __shared__ __align__(16) bf16 smem[24576];  // As 2x4096 | Bs 2x8192; Ct reuse
    const int z = blockIdx.z;
    const bf16*  W    = (z == 0) ? Wq : (z == 1) ? Wk : Wv;
    const float* bias = (z == 0) ? bq : (z == 1) ? bk : bv;

    int m0, n0;
    xcd_remap(blockIdx.x, blockIdx.y, m0, n0);
    const int t  = threadIdx.x;
    const int l  = t & 63, w = t >> 6;
    const int wr = w >> 2, wc = w & 3;
    const int lq = l >> 4, ln = l & 15;

    if (z < 2) {
        floatx4 acc[4][4] = {};
        gemm_core<1>(x, W, m0, n0, t, smem, smem + 8192, acc);
        bf16* out = (z == 0) ? qo : ko;
        const float sc = (z == 0) ? 0.125f * L2E : 1.0f;
#pragma unroll
        for (int j = 0; j < 4; ++j) {
            const int feat = n0 + wc * 64 + j * 16 + lq * 4;   // 4 consecutive
            const floatx4 bb = *(const floatx4*)&bias[feat];
            const int hh = feat >> 6, dd = feat & 63;
#pragma unroll
            for (int i = 0; i < 4; ++i) {
                const int xrow = m0 + wr * 64 + i * 16 + ln;
                const int bi = xrow >> 11, si = xrow & (Sc - 1);
                U64 pk;
#pragma unroll
                for (int r = 0; r < 4; ++r) pk.h[r] = (bf16)((acc[i][j][r] + bb[r]) * sc);
                *(intx2*)&out[(((size_t)bi * NHc + hh) * Sc + si) * HDc + dd] = pk.i;
            }
        }
    } else {
        floatx4 acc[4][4] = {};
        gemm_core<0>(x, W, m0, n0, t, smem, smem + 8192, acc);
        // transpose epilogue: Ct[64 cols][136 rows], four 64-col head-chunks
        bf16* Ct = smem;
        const int bi = m0 >> 11, s0 = m0 & (Sc - 1);
        for (int h2 = 0; h2 < 4; ++h2) {
            __syncthreads();
            if (wc == h2) {                       // 2 waves (wr=0,1)
#pragma unroll
                for (int j = 0; j < 4; ++j) {
                    const int c = j * 16 + ln;
                    const float bb = bias[n0 + h2 * 64 + c];
#pragma unroll
                    for (int i = 0; i < 4; ++i) {
                        U64 pk;
#pragma unroll
                        for (int r = 0; r < 4; ++r) pk.h[r] = (bf16)(acc[i][j][r] + bb);
                        *(intx2*)&Ct[c * 136 + wr * 64 + i * 16 + lq * 4] = pk.i;
                    }
                }
            }
            __syncthreads();
#pragma unroll
            for (int u = 0; u < 2; ++u) {
                const int id = t + 512 * u;           // 0..1023
                const int c = id >> 4, rg = id & 15;
                const int hh = (n0 >> 6) + h2;
                intx4 val = *(const intx4*)&Ct[c * 136 + rg * 8];
                *(intx4*)&vto[(((size_t)bi * NHc + hh) * HDc + c) * Sc + s0 + rg * 8] = val;
            }
        }
    }
}

// ---------------------------------------------------------------------------
// Output projection + bias + residual -> h (bf16), b64 loads/stores
// ---------------------------------------------------------------------------
__global__ __launch_bounds__(512, 4)
void oproj_gemm(const bf16* __restrict__ ctx, const bf16* __restrict__ Wo,
                const float* __restrict__ bo, const bf16* __restrict__ xb,
                bf16* __restrict__ hout)
{
    __shared__ __align__(16) bf16 smem[24576];
    int m0, n0;
    xcd_remap(blockIdx.x, blockIdx.y, m0, n0);
    const int t  = threadIdx.x;
    floatx4 acc[4][4] = {};
    gemm_core<1>(ctx, Wo, m0, n0, t, smem, smem + 8192, acc);

    const int l  = t & 63, w = t >> 6;
    const int wr = w >> 2, wc = w & 3;
    const int lq = l >> 4, ln = l & 15;
#pragma unroll
    for (int j = 0; j < 4; ++j) {
        const int col = n0 + wc * 64 + j * 16 + lq * 4;   // 4 consecutive
        const floatx4 bb = *(const floatx4*)&bo[col];
#pragma unroll
        for (int i = 0; i < 4; ++i) {
            const int row = m0 + wr * 64 + i * 16 + ln;
            U64 rx;
            rx.i = *(const intx2*)&xb[(size_t)row * Hc + col];
            U64 pk;
#pragma unroll
            for (int r = 0; r < 4; ++r)
                pk.h[r] = (bf16)(acc[i][j][r] + bb[r] + (float)rx.h[r]);
            *(intx2*)&hout[(size_t)row * Hc + col] = pk.i;
        }
    }
}

// ---------------------------------------------------------------------------
// Flash attention, S^T formulation, fixed-max softmax. (R9, unchanged --
// 91.5us verified; ones-MFMA denominator, swizzled K/V DMA dbuf, swizzled Pt.)
// ---------------------------------------------------------------------------
__global__ __launch_bounds__(256, 2)
void attention(const bf16* __restrict__ q, const bf16* __restrict__ k,
               const bf16* __restrict__ vt, const float* __restrict__ maskf,
               bf16* __restrict__ ctx)
{
    __shared__ __align__(16) bf16 Ks[2][64][64];   // [dbuf][kpos][hd] swizzled
    __shared__ __align__(16) bf16 Vs[2][64][64];   // [dbuf][d][kpos] swizzled
    __shared__ __align__(16) bf16 Pt[4][64][64];   // [wave][qrow][kpos] swizzled

    // XCD-aware remap: raw%8 = XCD; 8 consecutive (b,h) per XCD. 512%8==0.
    const int raw = blockIdx.x;                 // 0..511
    const int xcd = raw & 7, jj = raw >> 3;     // jj 0..63
    const int bh  = xcd * 8 + (jj >> 3);
    const int qt  = jj & 7;                     // q-tile of 256 rows
    const int b = bh >> 4, h = bh & 15;
    const int t = threadIdx.x, w = t >> 6, l = t & 63;
    const int lq = l >> 4, ln = l & 15;
    const int q0 = qt * 256 + w * 64;

    const bf16* kg = k  + (size_t)bh * Sc * HDc;
    const bf16* vg = vt + (size_t)bh * HDc * Sc;
    const float* mbase = maskf + b * Sc;        // pre-scaled by log2e

    // DMA staging geometry: wave w covers rows [16w,16w+16) in two 8-row
    // calls; dest lane-linear; LDS granule c of row r holds global granule
    // c^(r&7) via pre-swizzled global source column.
    const int rr  = l >> 3;
    const int gsw = ((l & 7) ^ rr) << 3;        // pre-swizzled global col (elems)
    const int r0  = w * 16 + rr, r1 = r0 + 8;
    const int dco = (l & 7) << 3;               // lane-linear LDS col (elems)
    const int sw  = ln & 7;                     // K/V read-side swizzle key
    const int pkey = sw << 1;                   // Pt granule XOR key (even)

    // Q fragments in registers (B-operand); q pre-scaled by 0.125*log2e
    bf16x8 qf[4][2];
#pragma unroll
    for (int qb = 0; qb < 4; ++qb)
#pragma unroll
        for (int kh = 0; kh < 2; ++kh)
            qf[qb][kh] = *(const bf16x8*)(q + ((size_t)bh * Sc + q0 + qb * 16 + ln) * HDc
                                            + kh * 32 + lq * 8);

    bf16x8 ones8;
#pragma unroll
    for (int jj2 = 0; jj2 < 8; ++jj2) ones8[jj2] = (bf16)1.0f;

    floatx4 o[4][4] = {};
    floatx4 accl[4] = {};

    auto stage = [&](int buf, int kt) {
        bf16* Kd = &Ks[buf][0][0];
        bf16* Vd = &Vs[buf][0][0];
        ld16(kg + (size_t)(kt * 64 + r0) * HDc + gsw, Kd + r0 * 64 + dco);
        ld16(kg + (size_t)(kt * 64 + r1) * HDc + gsw, Kd + r1 * 64 + dco);
        ld16(vg + (size_t)r0 * Sc + kt * 64 + gsw,    Vd + r0 * 64 + dco);
        ld16(vg + (size_t)r1 * Sc + kt * 64 + gsw,    Vd + r1 * 64 + dco);
    };

    stage(0, 0);
    int cur = 0;
    bf16* PtW = &Pt[w][0][0];                   // wave-private rows

    for (int kt = 0; kt < Sc / 64; ++kt) {
        __syncthreads();                 // drains own vmcnt -> buf[cur] ready
        if (kt + 1 < Sc / 64) stage(cur ^ 1, kt + 1);

        // mask (log2 domain): QK^T accumulator init (free add)
        floatx4 mvl[4];
#pragma unroll
        for (int cb = 0; cb < 4; ++cb)
            mvl[cb] = *(const floatx4*)(mbase + kt * 64 + cb * 16 + lq * 4);

        // K fragments once per tile, swizzled reads (conflict-free)
        bf16x8 kf[4][2];
#pragma unroll
        for (int cb = 0; cb < 4; ++cb)
#pragma unroll
            for (int kh = 0; kh < 2; ++kh)
                kf[cb][kh] = *(const bf16x8*)&Ks[cur][cb * 16 + ln]
                                               [((kh * 4 + lq) ^ sw) << 3];

        // per q-block: S^T = K*Q^T + mask -> exp2 -> swizzled Pt write
#pragma unroll
        for (int qb = 0; qb < 4; ++qb) {
            floatx4 s[4];
#pragma unroll
            for (int cb = 0; cb < 4; ++cb) s[cb] = mvl[cb];
            __builtin_amdgcn_s_setprio(1);
#pragma unroll
            for (int kh = 0; kh < 2; ++kh)
#pragma unroll
                for (int cb = 0; cb < 4; ++cb)
                    s[cb] = MFMA16(kf[cb][kh], qf[qb][kh], s[cb]);
            __builtin_amdgcn_s_setprio(0);
#pragma unroll
            for (int cb = 0; cb < 4; ++cb) {
                U64 pk;
#pragma unroll
                for (int r = 0; r < 4; ++r)
                    pk.h[r] = (bf16)__builtin_amdgcn_exp2f(s[cb][r]);
                // logical granule cb*4+lq (8B) -> phys granule ^(pkey)
                *(intx2*)(PtW + (qb * 16 + ln) * 64
                              + (((cb * 4 + lq) ^ pkey) << 2)) = pk.i;
            }
        }

        // V fragments once per tile, swizzled reads (conflict-free)
        bf16x8 vf[4][2];
#pragma unroll
        for (int db = 0; db < 4; ++db)
#pragma unroll
            for (int kh = 0; kh < 2; ++kh)
                vf[db][kh] = *(const bf16x8*)&Vs[cur][db * 16 + ln]
                                               [((kh * 4 + lq) ^ sw) << 3];

        // per q-block: O^T += V^T * P^T ; l += ones*P^T ; pf de-swizzles Pt
#pragma unroll
        for (int qb = 0; qb < 4; ++qb) {
            const bf16x8 pf0 = *(const bf16x8*)(PtW + (qb * 16 + ln) * 64
                                                    + (((2 * lq) ^ pkey) << 2));
            const bf16x8 pf1 = *(const bf16x8*)(PtW + (qb * 16 + ln) * 64
                                                    + (((8 + 2 * lq) ^ pkey) << 2));
            __builtin_amdgcn_s_setprio(1);
#pragma unroll
            for (int db = 0; db < 4; ++db) {
                o[qb][db] = MFMA16(vf[db][0], pf0, o[qb][db]);
                o[qb][db] = MFMA16(vf[db][1], pf1, o[qb][db]);
            }
            accl[qb] = MFMA16(ones8, pf0, accl[qb]);
            accl[qb] = MFMA16(ones8, pf1, accl[qb]);
            __builtin_amdgcn_s_setprio(0);
        }
        cur ^= 1;
    }

    // normalize + store ctx [B,S,H] (accl[qb][0] = full row denom)
#pragma unroll
    for (int qb = 0; qb < 4; ++qb) {
        const float li = 1.f / accl[qb][0];
        const int qg = q0 + qb * 16 + ln;
#pragma unroll
        for (int db = 0; db < 4; ++db) {
            U64 pk;
#pragma unroll
            for (int r = 0; r < 4; ++r) pk.h[r] = (bf16)(o[qb][db][r] * li);
            *(intx2*)&ctx[((size_t)b * Sc + qg) * Hc + h * HDc + db * 16 + lq * 4] = pk.i;
        }
    }
}

// ---------------------------------------------------------------------------
// LayerNorm; output dtype keyed off the inline per-block flag
// ---------------------------------------------------------------------------
__global__ __launch_bounds__(256)
void layernorm_k(const bf16* __restrict__ hbuf, const float* __restrict__ lw,
                 const float* __restrict__ lb, void* __restrict__ outp,
                 const void* __restrict__ xraw)
{
    __shared__ float wmx[4];
    __shared__ float ssum[4], ssq[4];
    const int fl = detect_flag_block(xraw, wmx);

    const int row = blockIdx.x;
    const int t = threadIdx.x;
    const bf16* hp = hbuf + (size_t)row * Hc;

    union { intx2 i2; bf16 e[4]; } pk;
    pk.i2 = *(const intx2*)(hp + t * 4);
    float v[4], sum = 0.f, sq = 0.f;
#pragma unroll
    for (int i = 0; i < 4; ++i) {
        v[i] = (float)pk.e[i];
        sum += v[i];
        sq  += v[i] * v[i];
    }
#pragma unroll
    for (int off = 1; off < 64; off <<= 1) {
        sum += __shfl_xor(sum, off, 64);
        sq  += __shfl_xor(sq,  off, 64);
    }
    const int w = t >> 6;
    if ((t & 63) == 0) { ssum[w] = sum; ssq[w] = sq; }
    __syncthreads();
    sum = ssum[0] + ssum[1] + ssum[2] + ssum[3];
    sq  = ssq[0]  + ssq[1]  + ssq[2]  + ssq[3];

    const float mean = sum * (1.f / (float)Hc);
    const float var  = sq * (1.f / (float)Hc) - mean * mean;
    const float rstd = rsqrtf(var + 1e-12f);

    float ov[4];
#pragma unroll
    for (int i = 0; i < 4; ++i) {
        const int c = t * 4 + i;
        ov[i] = lw[c] * (v[i] - mean) * rstd + lb[c];
    }
    if (fl) {
        float* of = (float*)outp + (size_t)row * Hc + t * 4;
#pragma unroll
        for (int i = 0; i < 4; ++i) of[i] = ov[i];
    } else {
        union { intx2 i2; bf16 e[4]; } po;
#pragma unroll
        for (int i = 0; i < 4; ++i) po.e[i] = (bf16)ov[i];
        *(intx2*)((bf16*)outp + (size_t)row * Hc + t * 4) = po.i2;
    }
}

// ---------------------------------------------------------------------------
extern "C" void kernel_launch(void* const* d_in, const int* in_sizes, int n_in,
                              void* d_out, int out_size, void* d_ws, size_t ws_size,
                              hipStream_t stream)
{
    const void* x    = d_in[0];
    const void* mask = d_in[1];
    const void* Wq   = d_in[2];
    const void* bq   = d_in[3];
    const void* Wk   = d_in[4];
    const void* bk   = d_in[5];
    const void* Wv   = d_in[6];
    const void* bv   = d_in[7];
    const void* Wo   = d_in[8];
    const void* bo   = d_in[9];
    const void* lnw  = d_in[10];
    const void* lnb  = d_in[11];

    char* ws = (char*)d_ws;
    const size_t MB = 1024 * 1024;
    float* maskf = (float*)(ws + 4096);
    float* bqf   = (float*)(ws + 64 * 1024);
    float* bkf   = bqf + Hc;
    float* bvf   = bkf + Hc;
    float* bof   = bvf + Hc;
    float* lnwf  = bof + Hc;
    float* lnbf  = lnwf + Hc;
    bf16* xb  = (bf16*)(ws + 1 * MB);    // 16 MB
    bf16* wqb = (bf16*)(ws + 17 * MB);   // 2 MB each, contiguous wq|wk|wv|wo
    bf16* wkb = (bf16*)(ws + 19 * MB);
    bf16* wvb = (bf16*)(ws + 21 * MB);
    bf16* wob = (bf16*)(ws + 23 * MB);
    bf16* qb  = (bf16*)(ws + 25 * MB);   // 16 MB
    bf16* kb  = (bf16*)(ws + 41 * MB);
    bf16* vtb = (bf16*)(ws + 57 * MB);   // V^T
    bf16* cb  = (bf16*)(ws + 73 * MB);   // ctx; high water 89 MB
    bf16* hb  = qb;                      // h reuses q (dead after attention)

    // one conversion dispatch: x | weights | mask+vectors (flag inline)
    conv_all_k<<<6153, 256, 0, stream>>>(x, Wq, Wk, Wv, Wo, mask,
                                         bq, bk, bv, bo, lnw, lnb,
                                         xb, wqb, maskf, bqf, bkf, bvf,
                                         bof, lnwf, lnbf);

    dim3 gqkv(Hc / 256, Mc / 128, 3);    // (4, 64, 3) = 768 blocks
    qkv_gemm<<<gqkv, 512, 0, stream>>>(xb, wqb, bqf, wkb, bkf, wvb, bvf, qb, kb, vtb);
    attention<<<dim3(Bc * NHc * (Sc / 256)), 256, 0, stream>>>(qb, kb, vtb, maskf, cb);
    oproj_gemm<<<dim3(Hc / 256, Mc / 128), 512, 0, stream>>>(cb, wob, bof, xb, hb);
    layernorm_k<<<dim3(Mc), 256, 0, stream>>>(hb, lnwf, lnbf, d_out, x);
}

// Round 11
// 282.988 us; speedup vs baseline: 1.0219x; 1.0219x over previous
//
#include <hip/hip_runtime.h>

typedef __bf16 bf16;
typedef __bf16 bf16x8 __attribute__((ext_vector_type(8)));
typedef __bf16 bf16x4 __attribute__((ext_vector_type(4)));
typedef float floatx4 __attribute__((ext_vector_type(4)));
typedef int   intx4  __attribute__((ext_vector_type(4)));
typedef int   intx2  __attribute__((ext_vector_type(2)));

#define MFMA16(a,b,c) __builtin_amdgcn_mfma_f32_16x16x32_bf16((a),(b),(c),0,0,0)

constexpr int Bc  = 4;
constexpr int Sc  = 2048;
constexpr int Hc  = 1024;
constexpr int NHc = 16;
constexpr int HDc = 64;
constexpr int Mc  = Bc * Sc;       // 8192 rows
constexpr int KIT = Hc / 32;       // 32 k-iterations
constexpr float L2E = 1.44269504088896f;

union U64  { bf16x4 h; intx2 i; };

// async global->LDS, 16B per lane (dest must be wave-uniform base + lane*16)
__device__ __forceinline__ void ld16(const bf16* g, bf16* l) {
    __builtin_amdgcn_global_load_lds(
        (const __attribute__((address_space(1))) void*)g,
        (__attribute__((address_space(3))) void*)l, 16, 0, 0);
}

// ---------------------------------------------------------------------------
// Inline per-block dtype detect: 256 threads read the first 256 ushorts of x
// (512B, L2-broadcast), treat each as truncated fp32, wave-parallel max.
// ---------------------------------------------------------------------------
__device__ __forceinline__ int detect_flag_block(const void* x, float* wmx)
{
    const unsigned short* xs = (const unsigned short*)x;
    const int tt = threadIdx.x;            // 256 threads, one value each
    unsigned int bits = ((unsigned int)xs[tt]) << 16;
    float v = __uint_as_float(bits);
    float a = isfinite(v) ? fabsf(v) : 1e30f;
#pragma unroll
    for (int off = 1; off < 64; off <<= 1)
        a = fmaxf(a, __shfl_xor(a, off, 64));
    if ((tt & 63) == 0) wmx[tt >> 6] = a;
    __syncthreads();
    const float m = fmaxf(fmaxf(wmx[0], wmx[1]), fmaxf(wmx[2], wmx[3]));
    __syncthreads();                       // wmx reusable after this
    return (m > 1e6f) ? 1 : 0;
}

// ---------------------------------------------------------------------------
// One merged conversion kernel: x (1048576 g8) | 4 weights (524288 g8) |
// mask+6 vectors (1792 g8)
// ---------------------------------------------------------------------------
__global__ __launch_bounds__(256)
void conv_all_k(const void* __restrict__ x,
                const void* __restrict__ Wq, const void* __restrict__ Wk,
                const void* __restrict__ Wv, const void* __restrict__ Wo,
                const void* __restrict__ mask,
                const void* __restrict__ bq, const void* __restrict__ bk,
                const void* __restrict__ bv, const void* __restrict__ bo,
                const void* __restrict__ lnw, const void* __restrict__ lnb,
                bf16* __restrict__ xb, bf16* __restrict__ wdst,
                float* maskf, float* bqf, float* bkf, float* bvf,
                float* bof, float* lnwf, float* lnbf)
{
    __shared__ float wmx[4];
    const int fl = detect_flag_block(x, wmx);

    const int g = blockIdx.x * 256 + threadIdx.x;
    if (g < 1048576) {
        if (fl) {
            const float* s = (const float*)x + (size_t)g * 8;
            union { intx4 v; bf16 e[8]; } o;
#pragma unroll
            for (int j = 0; j < 8; ++j) o.e[j] = (bf16)s[j];
            *(intx4*)(xb + (size_t)g * 8) = o.v;
        } else {
            *(intx4*)(xb + (size_t)g * 8) = *((const intx4*)x + g);
        }
    } else if (g < 1048576 + 524288) {
        const int gw = g - 1048576;
        const int wsel = gw >> 17, go = gw & 131071;
        const void* s = (wsel == 0) ? Wq : (wsel == 1) ? Wk : (wsel == 2) ? Wv : Wo;
        if (fl) {
            const float* sp = (const float*)s + (size_t)go * 8;
            union { intx4 v; bf16 e[8]; } o;
#pragma unroll
            for (int j = 0; j < 8; ++j) o.e[j] = (bf16)sp[j];
            *(intx4*)(wdst + (size_t)gw * 8) = o.v;
        } else {
            *(intx4*)(wdst + (size_t)gw * 8) = *((const intx4*)s + go);
        }
    } else {
        const int gs = g - 1048576 - 524288;
        if (gs >= 1792) return;
        const void* src; float* dst; int off; float scl = 1.0f;
        if (gs < 1024) { src = mask; dst = maskf; off = gs * 8; scl = L2E; }
        else {
            const int a = (gs - 1024) >> 7;
            off = ((gs - 1024) & 127) * 8;
            switch (a) {
                case 0: src = bq;  dst = bqf;  break;
                case 1: src = bk;  dst = bkf;  break;
                case 2: src = bv;  dst = bvf;  break;
                case 3: src = bo;  dst = bof;  break;
                case 4: src = lnw; dst = lnwf; break;
                default: src = lnb; dst = lnbf; break;
            }
        }
        if (fl) {
            const float* s = (const float*)src + off;
#pragma unroll
            for (int j = 0; j < 8; ++j) dst[off + j] = s[j] * scl;
        } else {
            union { intx4 v; bf16 e[8]; } u;
            u.v = *(const intx4*)((const bf16*)src + off);
#pragma unroll
            for (int j = 0; j < 8; ++j) dst[off + j] = (float)u.e[j] * scl;
        }
    }
}

// ---------------------------------------------------------------------------
// GEMM core: 128x128 tile over K=1024, A/W row-major. (R8 measured-best.)
// 2-phase pipelined: double-buffered LDS, stage(kb+1) issued BEFORE
// ds_read+MFMA of kb, ONE barrier per K-step.
// SWAP=0: acc[i][j] = C[xrow-block i][feat-block j]
// SWAP=1: acc[i][j] = C[feat-block j][xrow-block i] (lane cols = xrow)
// ---------------------------------------------------------------------------
template<int SWAP>
__device__ __forceinline__
void gemm_core(const bf16* __restrict__ A, const bf16* __restrict__ W,
               int m0, int n0, int t, bf16* As, bf16* Bs, floatx4 (&acc)[4][4])
{
    const int l  = t & 63, w = t >> 6;
    const int wr = w >> 1, wc = w & 1;
    const int lq = l >> 4, ln = l & 15;
    const int srow = t >> 2;            // 0..63
    const int scol = (t & 3) * 8;       // 0,8,16,24

    const bf16* a0 = A + (size_t)(m0 + srow) * Hc + scol;
    const bf16* b0 = W + (size_t)(n0 + srow) * Hc + scol;
    const int dst = srow * 32 + scol;   // lane-linear within a tile buffer

    auto stage = [&](int buf, int kb) {
        const int off = kb * 32;
        bf16* dA = As + buf * 4096;
        bf16* dB = Bs + buf * 4096;
        ld16(a0 + off,           dA + dst);
        ld16(a0 + 64 * Hc + off, dA + 64 * 32 + dst);
        ld16(b0 + off,           dB + dst);
        ld16(b0 + 64 * Hc + off, dB + 64 * 32 + dst);
    };

    stage(0, 0);
    int cur = 0;
    for (int kb = 0; kb < KIT; ++kb) {
        __syncthreads();                 // buf[cur] ready; buf[cur^1] readers done
        if (kb + 1 < KIT) stage(cur ^ 1, kb + 1);

        const bf16* Ab = As + cur * 4096;
        const bf16* Bb = Bs + cur * 4096;
        bf16x8 af[4], bw[4];
#pragma unroll
        for (int i = 0; i < 4; ++i)
            af[i] = *(const bf16x8*)&Ab[(wr * 64 + i * 16 + ln) * 32 + lq * 8];
#pragma unroll
        for (int j = 0; j < 4; ++j)
            bw[j] = *(const bf16x8*)&Bb[(wc * 64 + j * 16 + ln) * 32 + lq * 8];

        __builtin_amdgcn_s_setprio(1);
#pragma unroll
        for (int i = 0; i < 4; ++i)
#pragma unroll
            for (int j = 0; j < 4; ++j)
                acc[i][j] = SWAP ? MFMA16(bw[j], af[i], acc[i][j])
                                 : MFMA16(af[i], bw[j], acc[i][j]);
        __builtin_amdgcn_s_setprio(0);
        cur ^= 1;
    }
}

// chunked XCD remap for a (8 x 64) tile grid: each XCD owns 8 contiguous
// row-panels -> A-panel L2-resident per XCD, W fully L2-resident. Bijective.
__device__ __forceinline__ void xcd_remap(int bx, int by, int& m0, int& n0)
{
    const int flat = by * 8 + bx;            // dispatch-linear id, 0..511
    const int sw   = (flat & 7) * 64 + (flat >> 3);
    m0 = (sw >> 3) * 128;
    n0 = (sw & 7) * 128;
}

// ---------------------------------------------------------------------------
// Fused QKV: z=0 -> q (scaled by 0.125*log2e) [B,NH,S,HD]; z=1 -> k;
// z=2 -> V^T [B,NH,HD,S] via LDS transpose
// launch_bounds(256,3): R8's measured-best GEMM occupancy (3 blocks/CU).
// ---------------------------------------------------------------------------
__global__ __launch_bounds__(256, 3)
void qkv_gemm(const bf16* __restrict__ x,
              const bf16* __restrict__ Wq, const float* __restrict__ bq,
              const bf16* __restrict__ Wk, const float* __restrict__ bk,
              const bf16* __restrict__ Wv, const float* __restrict__ bv,
              bf16* __restrict__ qo, bf16* __restrict__ ko, bf16* __restrict__ vto)
{
    __shared__ __align__(16) bf16 smem[16384];  // 2 x (2x4096) dbuf; Ct reuse
    const int z = blockIdx.z;
    const bf16*  W    = (z == 0) ? Wq : (z == 1) ? Wk : Wv;
    const float* bias = (z == 0) ? bq : (z == 1) ? bk : bv;

    int m0, n0;
    xcd_remap(blockIdx.x, blockIdx.y, m0, n0);
    const int t  = threadIdx.x;
    const int l  = t & 63, w = t >> 6;
    const int wr = w >> 1, wc = w & 1;
    const int lq = l >> 4, ln = l & 15;

    if (z < 2) {
        floatx4 acc[4][4] = {};
        gemm_core<1>(x, W, m0, n0, t, smem, smem + 8192, acc);
        bf16* out = (z == 0) ? qo : ko;
        const float sc = (z == 0) ? 0.125f * L2E : 1.0f;
#pragma unroll
        for (int j = 0; j < 4; ++j) {
            const int feat = n0 + wc * 64 + j * 16 + lq * 4;   // 4 consecutive
            const floatx4 bb = *(const floatx4*)&bias[feat];
            const int hh = feat >> 6, dd = feat & 63;
#pragma unroll
            for (int i = 0; i < 4; ++i) {
                const int xrow = m0 + wr * 64 + i * 16 + ln;
                const int bi = xrow >> 11, si = xrow & (Sc - 1);
                U64 pk;
#pragma unroll
                for (int r = 0; r < 4; ++r) pk.h[r] = (bf16)((acc[i][j][r] + bb[r]) * sc);
                *(intx2*)&out[(((size_t)bi * NHc + hh) * Sc + si) * HDc + dd] = pk.i;
            }
        }
    } else {
        floatx4 acc[4][4] = {};
        gemm_core<0>(x, W, m0, n0, t, smem, smem + 8192, acc);
        // transpose epilogue: Ct[64 cols][136 rows], two col-halves
        bf16* Ct = smem;
        const int bi = m0 >> 11, s0 = m0 & (Sc - 1);
        for (int h2 = 0; h2 < 2; ++h2) {
            __syncthreads();
            if (wc == h2) {
#pragma unroll
                for (int j = 0; j < 4; ++j) {
                    const int c = j * 16 + ln;
                    const float bb = bias[n0 + h2 * 64 + c];
#pragma unroll
                    for (int i = 0; i < 4; ++i) {
                        U64 pk;
#pragma unroll
                        for (int r = 0; r < 4; ++r) pk.h[r] = (bf16)(acc[i][j][r] + bb);
                        *(intx2*)&Ct[c * 136 + wr * 64 + i * 16 + lq * 4] = pk.i;
                    }
                }
            }
            __syncthreads();
#pragma unroll
            for (int u = 0; u < 4; ++u) {
                const int id = t + 256 * u;           // 0..1023
                const int c = id >> 4, rg = id & 15;
                const int hh = (n0 >> 6) + h2;
                intx4 val = *(const intx4*)&Ct[c * 136 + rg * 8];
                *(intx4*)&vto[(((size_t)bi * NHc + hh) * HDc + c) * Sc + s0 + rg * 8] = val;
            }
        }
    }
}

// ---------------------------------------------------------------------------
// Output projection + bias + residual -> h (bf16), b64 loads/stores
// ---------------------------------------------------------------------------
__global__ __launch_bounds__(256, 3)
void oproj_gemm(const bf16* __restrict__ ctx, const bf16* __restrict__ Wo,
                const float* __restrict__ bo, const bf16* __restrict__ xb,
                bf16* __restrict__ hout)
{
    __shared__ __align__(16) bf16 smem[16384];
    int m0, n0;
    xcd_remap(blockIdx.x, blockIdx.y, m0, n0);
    const int t  = threadIdx.x;
    floatx4 acc[4][4] = {};
    gemm_core<1>(ctx, Wo, m0, n0, t, smem, smem + 8192, acc);

    const int l  = t & 63, w = t >> 6;
    const int wr = w >> 1, wc = w & 1;
    const int lq = l >> 4, ln = l & 15;
#pragma unroll
    for (int j = 0; j < 4; ++j) {
        const int col = n0 + wc * 64 + j * 16 + lq * 4;   // 4 consecutive
        const floatx4 bb = *(const floatx4*)&bo[col];
#pragma unroll
        for (int i = 0; i < 4; ++i) {
            const int row = m0 + wr * 64 + i * 16 + ln;
            U64 rx;
            rx.i = *(const intx2*)&xb[(size_t)row * Hc + col];
            U64 pk;
#pragma unroll
            for (int r = 0; r < 4; ++r)
                pk.h[r] = (bf16)(acc[i][j][r] + bb[r] + (float)rx.h[r]);
            *(intx2*)&hout[(size_t)row * Hc + col] = pk.i;
        }
    }
}

// ---------------------------------------------------------------------------
// Flash attention, S^T formulation, fixed-max softmax. (R9/R10, unchanged --
// 88-91.5us measured; ones-MFMA denominator, swizzled K/V DMA dbuf,
// swizzled Pt.)
// ---------------------------------------------------------------------------
__global__ __launch_bounds__(256, 2)
void attention(const bf16* __restrict__ q, const bf16* __restrict__ k,
               const bf16* __restrict__ vt, const float* __restrict__ maskf,
               bf16* __restrict__ ctx)
{
    __shared__ __align__(16) bf16 Ks[2][64][64];   // [dbuf][kpos][hd] swizzled
    __shared__ __align__(16) bf16 Vs[2][64][64];   // [dbuf][d][kpos] swizzled
    __shared__ __align__(16) bf16 Pt[4][64][64];   // [wave][qrow][kpos] swizzled

    // XCD-aware remap: raw%8 = XCD; 8 consecutive (b,h) per XCD. 512%8==0.
    const int raw = blockIdx.x;                 // 0..511
    const int xcd = raw & 7, jj = raw >> 3;     // jj 0..63
    const int bh  = xcd * 8 + (jj >> 3);
    const int qt  = jj & 7;                     // q-tile of 256 rows
    const int b = bh >> 4, h = bh & 15;
    const int t = threadIdx.x, w = t >> 6, l = t & 63;
    const int lq = l >> 4, ln = l & 15;
    const int q0 = qt * 256 + w * 64;

    const bf16* kg = k  + (size_t)bh * Sc * HDc;
    const bf16* vg = vt + (size_t)bh * HDc * Sc;
    const float* mbase = maskf + b * Sc;        // pre-scaled by log2e

    // DMA staging geometry: wave w covers rows [16w,16w+16) in two 8-row
    // calls; dest lane-linear; LDS granule c of row r holds global granule
    // c^(r&7) via pre-swizzled global source column.
    const int rr  = l >> 3;
    const int gsw = ((l & 7) ^ rr) << 3;        // pre-swizzled global col (elems)
    const int r0  = w * 16 + rr, r1 = r0 + 8;
    const int dco = (l & 7) << 3;               // lane-linear LDS col (elems)
    const int sw  = ln & 7;                     // K/V read-side swizzle key
    const int pkey = sw << 1;                   // Pt granule XOR key (even)

    // Q fragments in registers (B-operand); q pre-scaled by 0.125*log2e
    bf16x8 qf[4][2];
#pragma unroll
    for (int qb = 0; qb < 4; ++qb)
#pragma unroll
        for (int kh = 0; kh < 2; ++kh)
            qf[qb][kh] = *(const bf16x8*)(q + ((size_t)bh * Sc + q0 + qb * 16 + ln) * HDc
                                            + kh * 32 + lq * 8);

    bf16x8 ones8;
#pragma unroll
    for (int jj2 = 0; jj2 < 8; ++jj2) ones8[jj2] = (bf16)1.0f;

    floatx4 o[4][4] = {};
    floatx4 accl[4] = {};

    auto stage = [&](int buf, int kt) {
        bf16* Kd = &Ks[buf][0][0];
        bf16* Vd = &Vs[buf][0][0];
        ld16(kg + (size_t)(kt * 64 + r0) * HDc + gsw, Kd + r0 * 64 + dco);
        ld16(kg + (size_t)(kt * 64 + r1) * HDc + gsw, Kd + r1 * 64 + dco);
        ld16(vg + (size_t)r0 * Sc + kt * 64 + gsw,    Vd + r0 * 64 + dco);
        ld16(vg + (size_t)r1 * Sc + kt * 64 + gsw,    Vd + r1 * 64 + dco);
    };

    stage(0, 0);
    int cur = 0;
    bf16* PtW = &Pt[w][0][0];                   // wave-private rows

    for (int kt = 0; kt < Sc / 64; ++kt) {
        __syncthreads();                 // drains own vmcnt -> buf[cur] ready
        if (kt + 1 < Sc / 64) stage(cur ^ 1, kt + 1);

        // mask (log2 domain): QK^T accumulator init (free add)
        floatx4 mvl[4];
#pragma unroll
        for (int cb = 0; cb < 4; ++cb)
            mvl[cb] = *(const floatx4*)(mbase + kt * 64 + cb * 16 + lq * 4);

        // K fragments once per tile, swizzled reads (conflict-free)
        bf16x8 kf[4][2];
#pragma unroll
        for (int cb = 0; cb < 4; ++cb)
#pragma unroll
            for (int kh = 0; kh < 2; ++kh)
                kf[cb][kh] = *(const bf16x8*)&Ks[cur][cb * 16 + ln]
                                               [((kh * 4 + lq) ^ sw) << 3];

        // per q-block: S^T = K*Q^T + mask -> exp2 -> swizzled Pt write
#pragma unroll
        for (int qb = 0; qb < 4; ++qb) {
            floatx4 s[4];
#pragma unroll
            for (int cb = 0; cb < 4; ++cb) s[cb] = mvl[cb];
            __builtin_amdgcn_s_setprio(1);
#pragma unroll
            for (int kh = 0; kh < 2; ++kh)
#pragma unroll
                for (int cb = 0; cb < 4; ++cb)
                    s[cb] = MFMA16(kf[cb][kh], qf[qb][kh], s[cb]);
            __builtin_amdgcn_s_setprio(0);
#pragma unroll
            for (int cb = 0; cb < 4; ++cb) {
                U64 pk;
#pragma unroll
                for (int r = 0; r < 4; ++r)
                    pk.h[r] = (bf16)__builtin_amdgcn_exp2f(s[cb][r]);
                // logical granule cb*4+lq (8B) -> phys granule ^(pkey)
                *(intx2*)(PtW + (qb * 16 + ln) * 64
                              + (((cb * 4 + lq) ^ pkey) << 2)) = pk.i;
            }
        }

        // V fragments once per tile, swizzled reads (conflict-free)
        bf16x8 vf[4][2];
#pragma unroll
        for (int db = 0; db < 4; ++db)
#pragma unroll
            for (int kh = 0; kh < 2; ++kh)
                vf[db][kh] = *(const bf16x8*)&Vs[cur][db * 16 + ln]
                                               [((kh * 4 + lq) ^ sw) << 3];

        // per q-block: O^T += V^T * P^T ; l += ones*P^T ; pf de-swizzles Pt
#pragma unroll
        for (int qb = 0; qb < 4; ++qb) {
            const bf16x8 pf0 = *(const bf16x8*)(PtW + (qb * 16 + ln) * 64
                                                    + (((2 * lq) ^ pkey) << 2));
            const bf16x8 pf1 = *(const bf16x8*)(PtW + (qb * 16 + ln) * 64
                                                    + (((8 + 2 * lq) ^ pkey) << 2));
            __builtin_amdgcn_s_setprio(1);
#pragma unroll
            for (int db = 0; db < 4; ++db) {
                o[qb][db] = MFMA16(vf[db][0], pf0, o[qb][db]);
                o[qb][db] = MFMA16(vf[db][1], pf1, o[qb][db]);
            }
            accl[qb] = MFMA16(ones8, pf0, accl[qb]);
            accl[qb] = MFMA16(ones8, pf1, accl[qb]);
            __builtin_amdgcn_s_setprio(0);
        }
        cur ^= 1;
    }

    // normalize + store ctx [B,S,H] (accl[qb][0] = full row denom)
#pragma unroll
    for (int qb = 0; qb < 4; ++qb) {
        const float li = 1.f / accl[qb][0];
        const int qg = q0 + qb * 16 + ln;
#pragma unroll
        for (int db = 0; db < 4; ++db) {
            U64 pk;
#pragma unroll
            for (int r = 0; r < 4; ++r) pk.h[r] = (bf16)(o[qb][db][r] * li);
            *(intx2*)&ctx[((size_t)b * Sc + qg) * Hc + h * HDc + db * 16 + lq * 4] = pk.i;
        }
    }
}

// ---------------------------------------------------------------------------
// LayerNorm; output dtype keyed off the inline per-block flag
// ---------------------------------------------------------------------------
__global__ __launch_bounds__(256)
void layernorm_k(const bf16* __restrict__ hbuf, const float* __restrict__ lw,
                 const float* __restrict__ lb, void* __restrict__ outp,
                 const void* __restrict__ xraw)
{
    __shared__ float wmx[4];
    __shared__ float ssum[4], ssq[4];
    const int fl = detect_flag_block(xraw, wmx);

    const int row = blockIdx.x;
    const int t = threadIdx.x;
    const bf16* hp = hbuf + (size_t)row * Hc;

    union { intx2 i2; bf16 e[4]; } pk;
    pk.i2 = *(const intx2*)(hp + t * 4);
    float v[4], sum = 0.f, sq = 0.f;
#pragma unroll
    for (int i = 0; i < 4; ++i) {
        v[i] = (float)pk.e[i];
        sum += v[i];
        sq  += v[i] * v[i];
    }
#pragma unroll
    for (int off = 1; off < 64; off <<= 1) {
        sum += __shfl_xor(sum, off, 64);
        sq  += __shfl_xor(sq,  off, 64);
    }
    const int w = t >> 6;
    if ((t & 63) == 0) { ssum[w] = sum; ssq[w] = sq; }
    __syncthreads();
    sum = ssum[0] + ssum[1] + ssum[2] + ssum[3];
    sq  = ssq[0]  + ssq[1]  + ssq[2]  + ssq[3];

    const float mean = sum * (1.f / (float)Hc);
    const float var  = sq * (1.f / (float)Hc) - mean * mean;
    const float rstd = rsqrtf(var + 1e-12f);

    float ov[4];
#pragma unroll
    for (int i = 0; i < 4; ++i) {
        const int c = t * 4 + i;
        ov[i] = lw[c] * (v[i] - mean) * rstd + lb[c];
    }
    if (fl) {
        float* of = (float*)outp + (size_t)row * Hc + t * 4;
#pragma unroll
        for (int i = 0; i < 4; ++i) of[i] = ov[i];
    } else {
        union { intx2 i2; bf16 e[4]; } po;
#pragma unroll
        for (int i = 0; i < 4; ++i) po.e[i] = (bf16)ov[i];
        *(intx2*)((bf16*)outp + (size_t)row * Hc + t * 4) = po.i2;
    }
}

// ---------------------------------------------------------------------------
extern "C" void kernel_launch(void* const* d_in, const int* in_sizes, int n_in,
                              void* d_out, int out_size, void* d_ws, size_t ws_size,
                              hipStream_t stream)
{
    const void* x    = d_in[0];
    const void* mask = d_in[1];
    const void* Wq   = d_in[2];
    const void* bq   = d_in[3];
    const void* Wk   = d_in[4];
    const void* bk   = d_in[5];
    const void* Wv   = d_in[6];
    const void* bv   = d_in[7];
    const void* Wo   = d_in[8];
    const void* bo   = d_in[9];
    const void* lnw  = d_in[10];
    const void* lnb  = d_in[11];

    char* ws = (char*)d_ws;
    const size_t MB = 1024 * 1024;
    float* maskf = (float*)(ws + 4096);
    float* bqf   = (float*)(ws + 64 * 1024);
    float* bkf   = bqf + Hc;
    float* bvf   = bkf + Hc;
    float* bof   = bvf + Hc;
    float* lnwf  = bof + Hc;
    float* lnbf  = lnwf + Hc;
    bf16* xb  = (bf16*)(ws + 1 * MB);    // 16 MB
    bf16* wqb = (bf16*)(ws + 17 * MB);   // 2 MB each, contiguous wq|wk|wv|wo
    bf16* wkb = (bf16*)(ws + 19 * MB);
    bf16* wvb = (bf16*)(ws + 21 * MB);
    bf16* wob = (bf16*)(ws + 23 * MB);
    bf16* qb  = (bf16*)(ws + 25 * MB);   // 16 MB
    bf16* kb  = (bf16*)(ws + 41 * MB);
    bf16* vtb = (bf16*)(ws + 57 * MB);   // V^T
    bf16* cb  = (bf16*)(ws + 73 * MB);   // ctx; high water 89 MB
    bf16* hb  = qb;                      // h reuses q (dead after attention)

    // one conversion dispatch: x | weights | mask+vectors (flag inline)
    conv_all_k<<<6153, 256, 0, stream>>>(x, Wq, Wk, Wv, Wo, mask,
                                         bq, bk, bv, bo, lnw, lnb,
                                         xb, wqb, maskf, bqf, bkf, bvf,
                                         bof, lnwf, lnbf);

    dim3 gqkv(Hc / 128, Mc / 128, 3);
    qkv_gemm<<<gqkv, 256, 0, stream>>>(xb, wqb, bqf, wkb, bkf, wvb, bvf, qb, kb, vtb);
    attention<<<dim3(Bc * NHc * (Sc / 256)), 256, 0, stream>>>(qb, kb, vtb, maskf, cb);
    oproj_gemm<<<dim3(Hc / 128, Mc / 128), 256, 0, stream>>>(cb, wob, bof, xb, hb);
    layernorm_k<<<dim3(Mc), 256, 0, stream>>>(hb, lnwf, lnbf, d_out, x);
}